// Round 16
// baseline (41.147 us; speedup 1.0000x reference)
//
#include <hip/hip_runtime.h>
#include <math.h>

// HPSS fused — r13 structure + pruned sort + TILE LOOP (code-size fix).
// S (2,1,1025,2048) fp32. harm = median_31 along T (zero pad), perc = along F.
// outH = S*h^2/(h^2+p^2), outP = S*p^2/(h^2+p^2)   (softmask Z cancels).
//
// r13=35.2 / r14=36.9 / r15=36.4 attribution: noinline = ABI cost; the
// wave-private H->P handoff = lgkmcnt drain at the phase boundary. Both
// reverted: this is r13's exact phase structure (barriered H->P, fl=tid&31).
// NEW vs r13:
//  - #pragma unroll 1 loop over the 2 tiles: ONE inlined compute_tile
//    instance (~20KB, fits 32KB L1I) instead of two (~36KB, thrashes).
//    No ABI boundary (still forceinline). T14 prefetch kept: iteration 0
//    issues tile B's float4 loads before computing tile A.
//  - pruned Batcher-32 (a[31]=+INF inert -> drop CEs touching index 31).
// Core: RW=8 register-fed f32 slides (delete+insert, O(1) dep depth),
// float4 staging, fp16 hl container, grid 16x33x2 = 1056.

#define DIM_T 2048
#define DIM_F 1025
#define HALF 15
#define FT 32            // output f-rows per tile
#define TT 64            // output t-cols per tile
#define RW 8             // outputs per thread along sliding axis
#define TROWS (FT + 30)  // 62 staged rows
#define VPR 24           // float4 vecs per row (96 cols, [t0-16, t0+80))
#define TSTR 97          // dwords; odd -> conflict-free for both phases
#define HSTRH 66         // hl stride in halves (33 dwords, odd)
#define NVEC (TROWS * VPR)   // 1488
#define FEED (RW + 30)   // 38

typedef _Float16 h16;

__device__ __forceinline__ void ce(float& a, float& b) {
    const float mn = fminf(a, b);
    b = fmaxf(a, b);
    a = mn;
}

// Batcher-32 with all CEs touching index 31 pruned (a[31] = +INF is inert).
__device__ __forceinline__ void sort32(float (&a)[32]) {
#pragma unroll
    for (int p = 1; p < 32; p <<= 1) {
#pragma unroll
        for (int k = p; k >= 1; k >>= 1) {
#pragma unroll
            for (int j = k & (p - 1); j + k < 32; j += 2 * k) {
#pragma unroll
                for (int i = 0; i < k; ++i) {
                    if (i + j + k < 31) {   // ==31 CEs are no-ops
                        if ((i + j) / (2 * p) == (i + j + k) / (2 * p)) {
                            ce(a[i + j], a[i + j + k]);
                        }
                    }
                }
            }
        }
    }
}

// sorted-window slide: remove x_old (present in w[0..30]), insert x_new.
// w[31] must be +INF and is preserved. 31 indep (cmp+sel) + 31 indep med3.
__device__ __forceinline__ void slide(float (&w)[32], float x_old, float x_new) {
    float dprev = (w[0] < x_old) ? w[0] : w[1];
    float rprev = fminf(x_new, dprev);
#pragma unroll
    for (int i = 1; i < 31; ++i) {
        const float di = (w[i] < x_old) ? w[i] : w[i + 1];
        const float ri = __builtin_amdgcn_fmed3f(dprev, x_new, di);
        w[i - 1] = rprev;
        dprev = di;
        rprev = ri;
    }
    w[30] = rprev;
}

// load one staging vector for tile at t0x (vec index li = it*256+tid)
__device__ __forceinline__ float4 load_vec(const float* __restrict__ Sb,
                                           int f0, int t0x, int li) {
    float4 v = make_float4(0.f, 0.f, 0.f, 0.f);
    if (li < NVEC) {
        const int row = li / VPR;
        const int pos = li - row * VPR;
        const int f  = f0 - HALF + row;
        const int tg = t0x - 16 + pos * 4;
        if ((unsigned)f < (unsigned)DIM_F && (unsigned)tg <= (unsigned)(DIM_T - 4))
            v = *(const float4*)&Sb[(size_t)f * DIM_T + tg];
    }
    return v;
}

__device__ __forceinline__ void write_vec(float* __restrict__ tile, int li, float4 v) {
    if (li < NVEC) {
        const int row = li / VPR;
        const int pos = li - row * VPR;
        float* p = &tile[row * TSTR + pos * 4];
        p[0] = v.x; p[1] = v.y; p[2] = v.z; p[3] = v.w;
    }
}

// One 32x64 tile: H phase, barrier, P phase (r13's proven structure).
__device__ __forceinline__ void compute_tile(const float* __restrict__ tile,
                                             h16* __restrict__ hl,
                                             float* __restrict__ outH,
                                             float* __restrict__ outP,
                                             int tid, int f0, int b, int t0x) {
    // ---- phase H: harmonic medians (slide along t) -> hl[f][t] ----
    {
        const int fl = tid & 31;          // output f row 0..31
        const int tb = (tid >> 5) * RW;   // t chunk base 0..56
        const float* lr = tile + (fl + HALF) * TSTR + tb + 1;

        float r[FEED];
#pragma unroll
        for (int d = 0; d < FEED; ++d) r[d] = lr[d];

        float w[32];
        w[31] = INFINITY;
#pragma unroll
        for (int d = 0; d < 31; ++d) w[d] = r[d];
        sort32(w);
#pragma unroll
        for (int s = 0; s < RW; ++s) {
            hl[fl * HSTRH + tb + s] = (h16)w[15];
            if (s < RW - 1) slide(w, r[s], r[s + 31]);
        }
    }
    __syncthreads();
    // ---- phase P: percussive medians (slide along f) + combine + store ----
    {
        const int lane = tid & 63;        // t within tile
        const int fb   = (tid >> 6) * RW; // f chunk base 0,8,16,24
        const int t    = t0x + lane;

        float r[FEED];
#pragma unroll
        for (int d = 0; d < FEED; ++d) r[d] = tile[(fb + d) * TSTR + 16 + lane];
        h16 hp[RW];
#pragma unroll
        for (int s = 0; s < RW; ++s) hp[s] = hl[(fb + s) * HSTRH + lane];

        float w[32];
        w[31] = INFINITY;
#pragma unroll
        for (int d = 0; d < 31; ++d) w[d] = r[d];
        sort32(w);
#pragma unroll
        for (int s = 0; s < RW; ++s) {
            const int f = f0 + fb + s;
            if (f < DIM_F) {
                const float perc = w[15];
                const float harm = (float)hp[s];
                const float sv   = r[s + 15];   // center element, free
                const float h2 = harm * harm;
                const float p2 = perc * perc;
                const float inv = __builtin_amdgcn_rcpf(h2 + p2);  // 0 -> INF; (sv*0)*INF=NaN matches ref 0/0
                const size_t oi = ((size_t)b * DIM_F + f) * DIM_T + t;
                outH[oi] = sv * h2 * inv;
                outP[oi] = sv * p2 * inv;
            }
            if (s < RW - 1) slide(w, r[s], r[s + 31]);
        }
    }
}

__global__ __launch_bounds__(256, 4) void hpss_fused(const float* __restrict__ S,
                                                     float* __restrict__ outH,
                                                     float* __restrict__ outP) {
    __shared__ float tile[TROWS * TSTR];  // 24056 B
    __shared__ h16 hl[FT * HSTRH];        //  4224 B

    const int tid = threadIdx.x;
    const int t0A = blockIdx.x * (2 * TT);
    const int f0  = blockIdx.y * FT;
    const int b   = blockIdx.z;
    const float* __restrict__ Sb = S + (size_t)b * DIM_F * DIM_T;

    // prologue: load tile A into registers
    float4 bv[6];
#pragma unroll
    for (int it = 0; it < 6; ++it) bv[it] = load_vec(Sb, f0, t0A, it * 256 + tid);

    // ONE code instance of the tile pipeline (fits L1I); no ABI boundary.
#pragma unroll 1
    for (int ti = 0; ti < 2; ++ti) {
        const int t0x = t0A + ti * TT;
        // write staged registers -> LDS
#pragma unroll
        for (int it = 0; it < 6; ++it) write_vec(tile, it * 256 + tid, bv[it]);
        // T14: issue tile B's global loads before computing tile A
        if (ti == 0) {
#pragma unroll
            for (int it = 0; it < 6; ++it)
                bv[it] = load_vec(Sb, f0, t0A + TT, it * 256 + tid);
        }
        __syncthreads();
        compute_tile(tile, hl, outH, outP, tid, f0, b, t0x);
        __syncthreads();   // all waves done reading tile before next overwrite
    }
}

extern "C" void kernel_launch(void* const* d_in, const int* in_sizes, int n_in,
                              void* d_out, int out_size, void* d_ws, size_t ws_size,
                              hipStream_t stream) {
    const float* S = (const float*)d_in[0];
    float* outH = (float*)d_out;
    float* outP = outH + (size_t)2 * DIM_F * DIM_T;

    dim3 grid(DIM_T / (2 * TT), (DIM_F + FT - 1) / FT, 2);  // 16 x 33 x 2 = 1056
    hpss_fused<<<grid, 256, 0, stream>>>(S, outH, outP);
}

// Round 17
// 35.320 us; speedup vs baseline: 1.1650x; 1.1650x over previous
//
#include <hip/hip_runtime.h>
#include <math.h>

// HPSS fused — EXACT r13 structure (best: 35.2us) + pruned Batcher sort.
// S (2,1,1025,2048) fp32. harm = median_31 along T (zero pad), perc = along F.
// outH = S*h^2/(h^2+p^2), outP = S*p^2/(h^2+p^2)   (softmask Z cancels).
//
// Attribution r13-r16: every structural deviation from r13's straight-line
// fully-unrolled 2-tile body regressed via register-pressure side effects
// (r14 noinline: ABI save/restore; r15 wave-private: lgkmcnt drain at phase
// boundary; r16 unroll-1 loop: bv[] live across loop -> 25MB scratch,
// VGPR 64, bank-conflict spike). This round: r13 verbatim, ONE change —
// the sort prune (CEs touching index 31 are no-ops on the +INF sentinel;
// 191 -> 176 CEs, -120 VALU/thread), validated correct in r14/r15/r16.
// Core: RW=8 register-fed f32 slides (delete+insert, O(1) dep depth),
// float4 staging, T14 2-tile prefetch, fp16 hl container (median commutes
// with monotone cast), 32(f)x64(t) tiles x2/block, grid 16x33x2 = 1056.

#define DIM_T 2048
#define DIM_F 1025
#define HALF 15
#define FT 32            // output f-rows per tile
#define TT 64            // output t-cols per tile
#define RW 8             // outputs per thread along sliding axis
#define TROWS (FT + 30)  // 62 staged rows
#define VPR 24           // float4 vecs per row (96 cols, [t0-16, t0+80))
#define TSTR 97          // dwords; odd -> conflict-free for both phases
#define HSTRH 66         // hl stride in halves (33 dwords, odd)
#define NVEC (TROWS * VPR)   // 1488
#define FEED (RW + 30)   // 38

typedef _Float16 h16;

__device__ __forceinline__ void ce(float& a, float& b) {
    const float mn = fminf(a, b);
    b = fmaxf(a, b);
    a = mn;
}

// Batcher-32 with all CEs touching index 31 pruned (a[31] = +INF is inert).
__device__ __forceinline__ void sort32(float (&a)[32]) {
#pragma unroll
    for (int p = 1; p < 32; p <<= 1) {
#pragma unroll
        for (int k = p; k >= 1; k >>= 1) {
#pragma unroll
            for (int j = k & (p - 1); j + k < 32; j += 2 * k) {
#pragma unroll
                for (int i = 0; i < k; ++i) {
                    if (i + j + k < 31) {   // ==31 CEs are no-ops on +INF
                        if ((i + j) / (2 * p) == (i + j + k) / (2 * p)) {
                            ce(a[i + j], a[i + j + k]);
                        }
                    }
                }
            }
        }
    }
}

// sorted-window slide: remove x_old (present in w[0..30]), insert x_new.
// w[31] must be +INF and is preserved. 31 indep (cmp+sel) + 31 indep med3.
__device__ __forceinline__ void slide(float (&w)[32], float x_old, float x_new) {
    float dprev = (w[0] < x_old) ? w[0] : w[1];
    float rprev = fminf(x_new, dprev);
#pragma unroll
    for (int i = 1; i < 31; ++i) {
        const float di = (w[i] < x_old) ? w[i] : w[i + 1];
        const float ri = __builtin_amdgcn_fmed3f(dprev, x_new, di);
        w[i - 1] = rprev;
        dprev = di;
        rprev = ri;
    }
    w[30] = rprev;
}

// load one staging vector for tile at t0x (vec index li = it*256+tid)
__device__ __forceinline__ float4 load_vec(const float* __restrict__ Sb,
                                           int f0, int t0x, int li) {
    float4 v = make_float4(0.f, 0.f, 0.f, 0.f);
    if (li < NVEC) {
        const int row = li / VPR;
        const int pos = li - row * VPR;
        const int f  = f0 - HALF + row;
        const int tg = t0x - 16 + pos * 4;
        if ((unsigned)f < (unsigned)DIM_F && (unsigned)tg <= (unsigned)(DIM_T - 4))
            v = *(const float4*)&Sb[(size_t)f * DIM_T + tg];
    }
    return v;
}

__device__ __forceinline__ void write_vec(float* __restrict__ tile, int li, float4 v) {
    if (li < NVEC) {
        const int row = li / VPR;
        const int pos = li - row * VPR;
        float* p = &tile[row * TSTR + pos * 4];
        p[0] = v.x; p[1] = v.y; p[2] = v.z; p[3] = v.w;
    }
}

// One 32x64 tile: H phase, barrier, P phase (r13's proven structure).
__device__ __forceinline__ void compute_tile(const float* __restrict__ tile,
                                             h16* __restrict__ hl,
                                             float* __restrict__ outH,
                                             float* __restrict__ outP,
                                             int tid, int f0, int b, int t0x) {
    // ---- phase H: harmonic medians (slide along t) -> hl[f][t] ----
    {
        const int fl = tid & 31;          // output f row 0..31
        const int tb = (tid >> 5) * RW;   // t chunk base 0..56
        const float* lr = tile + (fl + HALF) * TSTR + tb + 1;

        float r[FEED];
#pragma unroll
        for (int d = 0; d < FEED; ++d) r[d] = lr[d];

        float w[32];
        w[31] = INFINITY;
#pragma unroll
        for (int d = 0; d < 31; ++d) w[d] = r[d];
        sort32(w);
#pragma unroll
        for (int s = 0; s < RW; ++s) {
            hl[fl * HSTRH + tb + s] = (h16)w[15];
            if (s < RW - 1) slide(w, r[s], r[s + 31]);
        }
    }
    __syncthreads();
    // ---- phase P: percussive medians (slide along f) + combine + store ----
    {
        const int lane = tid & 63;        // t within tile
        const int fb   = (tid >> 6) * RW; // f chunk base 0,8,16,24
        const int t    = t0x + lane;

        float r[FEED];
#pragma unroll
        for (int d = 0; d < FEED; ++d) r[d] = tile[(fb + d) * TSTR + 16 + lane];
        h16 hp[RW];
#pragma unroll
        for (int s = 0; s < RW; ++s) hp[s] = hl[(fb + s) * HSTRH + lane];

        float w[32];
        w[31] = INFINITY;
#pragma unroll
        for (int d = 0; d < 31; ++d) w[d] = r[d];
        sort32(w);
#pragma unroll
        for (int s = 0; s < RW; ++s) {
            const int f = f0 + fb + s;
            if (f < DIM_F) {
                const float perc = w[15];
                const float harm = (float)hp[s];
                const float sv   = r[s + 15];   // center element, free
                const float h2 = harm * harm;
                const float p2 = perc * perc;
                const float inv = __builtin_amdgcn_rcpf(h2 + p2);  // 0 -> INF; (sv*0)*INF=NaN matches ref 0/0
                const size_t oi = ((size_t)b * DIM_F + f) * DIM_T + t;
                outH[oi] = sv * h2 * inv;
                outP[oi] = sv * p2 * inv;
            }
            if (s < RW - 1) slide(w, r[s], r[s + 31]);
        }
    }
}

__global__ __launch_bounds__(256, 4) void hpss_fused(const float* __restrict__ S,
                                                     float* __restrict__ outH,
                                                     float* __restrict__ outP) {
    __shared__ float tile[TROWS * TSTR];  // 24056 B
    __shared__ h16 hl[FT * HSTRH];        //  4224 B

    const int tid = threadIdx.x;
    const int t0A = blockIdx.x * (2 * TT);      // tile A
    const int t0B = t0A + TT;                   // tile B
    const int f0  = blockIdx.y * FT;
    const int b   = blockIdx.z;
    const float* __restrict__ Sb = S + (size_t)b * DIM_F * DIM_T;

    // stage tile A directly
#pragma unroll
    for (int it = 0; it < 6; ++it)
        write_vec(tile, it * 256 + tid, load_vec(Sb, f0, t0A, it * 256 + tid));

    // issue tile B loads NOW; consumed a full compute-phase later (T14)
    float4 bv[6];
#pragma unroll
    for (int it = 0; it < 6; ++it) bv[it] = load_vec(Sb, f0, t0B, it * 256 + tid);

    __syncthreads();
    compute_tile(tile, hl, outH, outP, tid, f0, b, t0A);
    __syncthreads();                    // all waves done reading tile A

#pragma unroll
    for (int it = 0; it < 6; ++it) write_vec(tile, it * 256 + tid, bv[it]);
    __syncthreads();
    compute_tile(tile, hl, outH, outP, tid, f0, b, t0B);
}

extern "C" void kernel_launch(void* const* d_in, const int* in_sizes, int n_in,
                              void* d_out, int out_size, void* d_ws, size_t ws_size,
                              hipStream_t stream) {
    const float* S = (const float*)d_in[0];
    float* outH = (float*)d_out;
    float* outP = outH + (size_t)2 * DIM_F * DIM_T;

    dim3 grid(DIM_T / (2 * TT), (DIM_F + FT - 1) / FT, 2);  // 16 x 33 x 2 = 1056
    hpss_fused<<<grid, 256, 0, stream>>>(S, outH, outP);
}